// Round 1
// baseline (972.426 us; speedup 1.0000x reference)
//
#include <hip/hip_runtime.h>
#include <stdint.h>
#include <math.h>

// Problem constants (match reference)
#define EDGES 563200
#define NNODES 17600    // B*(NW+NS)
#define OUT0SZ 2640000  // 17600*150
#define MROWS 64000     // 1600 sentences * 40 positions
#define MPAD  64016     // + zero pad rows for window overhang
#define KSTRIDE 2112    // B pack row stride (halfs)

typedef _Float16 h2 __attribute__((ext_vector_type(2)));
typedef _Float16 h4 __attribute__((ext_vector_type(4)));
typedef _Float16 v8h __attribute__((ext_vector_type(8)));
typedef float v4f __attribute__((ext_vector_type(4)));

__device__ __forceinline__ float sigm(float x){ return 1.f / (1.f + expf(-x)); }

__device__ __forceinline__ float fdot2_(h2 a, h2 b, float c){
#if __has_builtin(__builtin_amdgcn_fdot2)
  return __builtin_amdgcn_fdot2(a, b, c, false);
#else
  return c + (float)a.x * (float)b.x + (float)a.y * (float)b.y;
#endif
}

// ---------------- POS table (numpy float64 sinusoid, row 0 zeroed) ----------
__global__ void gcnk_postab(float* __restrict__ pos){
  int idx = blockIdx.x * 256 + threadIdx.x;
  if (idx >= 513 * 300) return;
  int p = idx / 300, i = idx - p * 300;
  float v = 0.f;
  if (p != 0){
    double expo = (double)(2 * (i / 2)) / 300.0;
    double ang = (double)p / pow(10000.0, expo);
    v = (float)((i & 1) ? cos(ang) : sin(ang));
  }
  pos[idx] = v;
}

// ---------------- sentlen + glen --------------------------------------------
__global__ void gcnk_prep(const int* __restrict__ sx, int* __restrict__ sentlen,
                          int* __restrict__ glen){
  int tid = blockIdx.x * 256 + threadIdx.x;
  if (tid < 1600){
    int c = 0;
    for (int j = 0; j < 40; j++) c += (sx[tid * 40 + j] != 0);
    sentlen[tid] = c;
  } else if (tid < 1632){
    int b = tid - 1600, c = 0;
    for (int s = 0; s < 50; s++) c += (sx[b * 2000 + s * 40] != 0);
    glen[b] = c;
  }
}

__global__ void gcnk_rowmap(const int* __restrict__ glen, int* __restrict__ rowmap){
  int i = blockIdx.x * 256 + threadIdx.x;
  if (i >= 1600) return;
  int b = i / 50, t = i - b * 50, g = glen[b];
  rowmap[i] = b * 50 + ((t < g) ? (g - 1 - t) : t);
}

// ---------------- emb_words output ------------------------------------------
__global__ void gcnk_embw(const int* __restrict__ x, const float* __restrict__ tab,
                          float4* __restrict__ out){
  int idx = blockIdx.x * 256 + threadIdx.x;
  if (idx >= 16000 * 75) return;
  int row = idx / 75, q = idx - row * 75;
  const float4* t = (const float4*)tab;
  out[idx] = t[x[row] * 75 + q];
}

// ---------------- generic zero ----------------------------------------------
__global__ void gcnk_zeroi(unsigned int* __restrict__ p, int n){
  int i = blockIdx.x * 256 + threadIdx.x;
  if (i < n) p[i] = 0u;
}

// ---------------- enc (fp16): enc[m][d] = tab[tok]+pos, pad rows zero -------
__global__ void gcnk_ench(const int* __restrict__ sx, const float* __restrict__ tab,
                          const float* __restrict__ pos, const int* __restrict__ sentlen,
                          _Float16* __restrict__ ench){
  int idx = blockIdx.x * 256 + threadIdx.x;
  if (idx >= MPAD * 75) return;
  int row = idx / 75, q = idx - row * 75;
  int d = q * 4;
  h4 o; o[0] = (_Float16)0.f; o[1] = (_Float16)0.f; o[2] = (_Float16)0.f; o[3] = (_Float16)0.f;
  if (row < MROWS){
    int n = row / 40, l = row - n * 40;
    int tok = sx[n * 40 + l];
    int p = (l < sentlen[n]) ? (l + 1) : 0;
    float4 a = *(const float4*)(tab + (size_t)tok * 300 + d);
    float4 b = *(const float4*)(pos + (size_t)p * 300 + d);
    o[0] = (_Float16)(a.x + b.x); o[1] = (_Float16)(a.y + b.y);
    o[2] = (_Float16)(a.z + b.z); o[3] = (_Float16)(a.w + b.w);
  }
  *(h4*)(ench + (size_t)row * 300 + d) = o;
}

// ---------------- pack conv weights: Bp[2][160][2112] fp16 + bias[320] ------
// group g holds heads 3g+2..3g+4 (cols 0..149), cols 150..159 zero.
__global__ void gcnk_bpack(const float* w2, const float* w3, const float* w4,
                           const float* w5, const float* w6, const float* w7,
                           const float* c2, const float* c3, const float* c4,
                           const float* c5, const float* c6, const float* c7,
                           _Float16* __restrict__ Bp, float* __restrict__ bias_p){
  int idx = blockIdx.x * 256 + threadIdx.x;
  if (idx < 2 * 160 * KSTRIDE){
    int n = idx / KSTRIDE, kk = idx - n * KSTRIDE;
    int g = n / 160, c = n - g * 160;
    _Float16 v = (_Float16)0.f;
    if (c < 150){
      int H = 3 * g + 2 + c / 50, o = c % 50;
      if (kk < 300 * H){
        const float* w;
        switch (H){ case 2: w = w2; break; case 3: w = w3; break;
                    case 4: w = w4; break; case 5: w = w5; break;
                    case 6: w = w6; break; default: w = w7; break; }
        v = (_Float16)w[o * 300 * H + kk];
      }
    }
    Bp[idx] = v;
  }
  if (idx < 320){
    int g = idx / 160, c = idx - g * 160;
    float bv = 0.f;
    if (c < 150){
      int H = 3 * g + 2 + c / 50, o = c % 50;
      const float* cbp;
      switch (H){ case 2: cbp = c2; break; case 3: cbp = c3; break;
                  case 4: cbp = c4; break; case 5: cbp = c5; break;
                  case 6: cbp = c6; break; default: cbp = c7; break; }
      bv = cbp[o];
    }
    bias_p[idx] = bv;
  }
}

// ---------------- fused conv GEMM via MFMA f16 ------------------------------
// BM=64: whole A footprint (contiguous 45056B thanks to implicit im2col) is
// staged into LDS ONCE; B fragments are read directly from global (L2) with a
// 2-chunk double-buffered prefetch. Zero barriers inside the K loop.
__global__ __launch_bounds__(256)
void gcnk_convmfma(const _Float16* __restrict__ A, const _Float16* __restrict__ Bp,
                   const float* __restrict__ bias_p, unsigned int* __restrict__ ngram_u){
  __shared__ __align__(16) char smem[45056];   // 11 * 4096; >= (64+7)*600 + slack
  float* Cs = (float*)smem;                    // epilogue reuse: [64][33]
  const int tid = threadIdx.x;
  const int m0 = blockIdx.x * 64;
  const int grp = blockIdx.y;
  const _Float16* Bg = Bp + (size_t)grp * 160 * KSTRIDE;
  const int kmax = grp ? 2112 : 1216;          // heads 2-4 need K<=1200
  const int w = tid >> 6, lane = tid & 63;
  const int wm = (w >> 1) * 32, wn = (w & 1) * 80;
  const int fm = lane & 15, fq = lane >> 4;

  // ---- stage A footprint once: linear copy, 16B/thread x 11 iters ----
  {
    const uint4* gp = (const uint4*)(A + (size_t)m0 * 300);
    uint4* lp = (uint4*)smem;
    #pragma unroll
    for (int j = 0; j < 11; j++)
      lp[j * 256 + tid] = gp[j * 256 + tid];
  }
  __syncthreads();

  v4f acc[2][5] = {};
  const _Float16* bptr[5];
  #pragma unroll
  for (int nt = 0; nt < 5; nt++)
    bptr[nt] = Bg + (size_t)(wn + nt * 16 + fm) * KSTRIDE + fq * 8;
  const int aoff0 = (wm + fm) * 600 + fq * 16;       // byte offsets into LDS
  const int aoff1 = aoff0 + 16 * 600;

  auto loadB = [&](v8h* dst, int k){
    #pragma unroll
    for (int nt = 0; nt < 5; nt++) dst[nt] = *(const v8h*)(bptr[nt] + k);
  };
  auto step = [&](int kc2, v8h* bf){
    const char* p0 = smem + aoff0 + kc2 * 2;
    const char* p1 = smem + aoff1 + kc2 * 2;
    union { uint2 u[2]; v8h v; } a0, a1;       // rows only 8B-aligned (600B stride)
    a0.u[0] = *(const uint2*)p0; a0.u[1] = *(const uint2*)(p0 + 8);
    a1.u[0] = *(const uint2*)p1; a1.u[1] = *(const uint2*)(p1 + 8);
    #pragma unroll
    for (int nt = 0; nt < 5; nt++){
      acc[0][nt] = __builtin_amdgcn_mfma_f32_16x16x32_f16(a0.v, bf[nt], acc[0][nt], 0, 0, 0);
      acc[1][nt] = __builtin_amdgcn_mfma_f32_16x16x32_f16(a1.v, bf[nt], acc[1][nt], 0, 0, 0);
    }
  };

  v8h bX[5], bY[5];
  loadB(bX, 0);
  loadB(bY, 32);
  for (int kc = 0; kc < kmax; kc += 64){       // kmax % 64 == 0 for both groups
    step(kc, bX);
    if (kc + 64 < kmax) loadB(bX, kc + 64);
    step(kc + 32, bY);
    if (kc + 96 < kmax) loadB(bY, kc + 96);
  }

  // epilogue: 5 passes of 32 cols through LDS; relu+window-max -> atomicMax
  for (int p = 0; p < 5; p++){
    __syncthreads();
    #pragma unroll
    for (int nt = 0; nt < 5; nt++){
      int cstart = wn + nt * 16;
      if ((cstart >> 5) == p){
        int co = cstart - p * 32 + fm;
        #pragma unroll
        for (int mt = 0; mt < 2; mt++)
          #pragma unroll
          for (int r = 0; r < 4; r++)
            Cs[(wm + mt * 16 + fq * 4 + r) * 33 + co] = acc[mt][nt][r];
      }
    }
    __syncthreads();
    if (tid < 96){
      int cl = tid & 31, si = tid >> 5;        // 3 sentences can touch a 64-row tile
      int col = p * 32 + cl;                   // group-local col
      if (col < 150){
        int H = 3 * grp + 2 + col / 50, lh = 41 - H;
        int sent = m0 / 40 + si;
        if (sent < 1600){
          int rlo = sent * 40; if (rlo < m0) rlo = m0;
          int rhi = sent * 40 + lh; if (rhi > m0 + 64) rhi = m0 + 64;
          if (rlo < rhi){
            float bv = bias_p[grp * 160 + col];
            float vmax = 0.f;
            for (int r = rlo; r < rhi; r++){
              float v = Cs[(r - m0) * 33 + cl] + bv;
              vmax = fmaxf(vmax, v);
            }
            atomicMax(ngram_u + sent * 300 + grp * 150 + col, __float_as_uint(vmax));
          }
        }
      }
    }
  }
}

// ngram += POS_TAB[n % 50]
__global__ void gcnk_addpos(float* __restrict__ ngram, const float* __restrict__ pos){
  int idx = blockIdx.x * 256 + threadIdx.x;
  if (idx >= 1600 * 300) return;
  int row = idx / 300, d = idx - row * 300;
  ngram[idx] += pos[(row % 50) * 300 + d];
}

// ---------------- MFMA GEMM: C[M,N] = A[M,K](fp32->fp16) @ Wt[N,K]^T + b ----
// OUTH=1: write fp16 with row stride 160 (for the GCN aggregation gather).
template<int BM, int BN, int WMT, int WNT, int OUTH>
__global__ __launch_bounds__(256)
void gcnk_mgemm(const float* __restrict__ A, const float* __restrict__ Wt,
                const float* __restrict__ b1, const float* __restrict__ b2,
                void* __restrict__ Cv, int M, int N, int K){
  __shared__ __align__(16) _Float16 As[BM * 40];
  __shared__ __align__(16) _Float16 Bs[BN * 40];
  const int tid = threadIdx.x;
  const int m0 = blockIdx.x * BM, n0 = blockIdx.y * BN;
  const int w = tid >> 6, lane = tid & 63;
  const int wm = (w >> 1) * (WMT * 16), wn = (w & 1) * (WNT * 16);
  const int fm = lane & 15, fq = lane >> 4;
  v4f acc[WMT][WNT] = {};
  const int nch = (K + 31) >> 5;
  for (int ch = 0; ch < nch; ch++){
    int kc = ch * 32;
    #pragma unroll
    for (int j = 0; j < BM / 64; j++){      // A stage: BM rows x 32 halfs
      int u = tid + 256 * j;
      int row = u >> 2, cb = (u & 3) * 8;
      int gm = m0 + row, gk = kc + cb;
      v8h vv;
      if (gm < M && gk + 8 <= K){
        const float* p = A + (size_t)gm * K + gk;
        #pragma unroll
        for (int e = 0; e < 8; e++) vv[e] = (_Float16)p[e];
      } else {
        #pragma unroll
        for (int e = 0; e < 8; e++)
          vv[e] = (gm < M && gk + e < K) ? (_Float16)A[(size_t)gm * K + gk + e] : (_Float16)0.f;
      }
      *(v8h*)(As + row * 40 + cb) = vv;
    }
    {                                        // B stage: BN(=64) rows x 32 halfs
      int row = tid >> 2, cb = (tid & 3) * 8;
      int gn = n0 + row, gk = kc + cb;
      v8h vv;
      if (gn < N && gk + 8 <= K){
        const float* p = Wt + (size_t)gn * K + gk;
        #pragma unroll
        for (int e = 0; e < 8; e++) vv[e] = (_Float16)p[e];
      } else {
        #pragma unroll
        for (int e = 0; e < 8; e++)
          vv[e] = (gn < N && gk + e < K) ? (_Float16)Wt[(size_t)gn * K + gk + e] : (_Float16)0.f;
      }
      *(v8h*)(Bs + row * 40 + cb) = vv;
    }
    __syncthreads();
    v8h af[WMT], bf[WNT];
    #pragma unroll
    for (int mt = 0; mt < WMT; mt++)
      af[mt] = *(const v8h*)(As + (wm + mt * 16 + fm) * 40 + fq * 8);
    #pragma unroll
    for (int nt = 0; nt < WNT; nt++)
      bf[nt] = *(const v8h*)(Bs + (wn + nt * 16 + fm) * 40 + fq * 8);
    #pragma unroll
    for (int mt = 0; mt < WMT; mt++)
      #pragma unroll
      for (int nt = 0; nt < WNT; nt++)
        acc[mt][nt] = __builtin_amdgcn_mfma_f32_16x16x32_f16(af[mt], bf[nt], acc[mt][nt], 0, 0, 0);
    __syncthreads();
  }
  #pragma unroll
  for (int nt = 0; nt < WNT; nt++){
    int gn = n0 + wn + nt * 16 + fm;
    if (gn >= N) continue;
    float badd = (b1 ? b1[gn] : 0.f) + (b2 ? b2[gn] : 0.f);
    #pragma unroll
    for (int mt = 0; mt < WMT; mt++)
      #pragma unroll
      for (int r = 0; r < 4; r++){
        int gm = m0 + wm + mt * 16 + fq * 4 + r;
        if (gm < M){
          float val = acc[mt][nt][r] + badd;
          if (OUTH) ((_Float16*)Cv)[(size_t)gm * 160 + gn] = (_Float16)val;
          else      ((float*)Cv)[(size_t)gm * N + gn] = val;
        }
      }
  }
}

// ---------------- row permute / concat --------------------------------------
__global__ void gcnk_permute150(float* __restrict__ dst, const float* __restrict__ src,
                                const int* __restrict__ map){
  int idx = blockIdx.x * 256 + threadIdx.x;
  if (idx >= 1600 * 150) return;
  int row = idx / 150, d = idx - row * 150;
  dst[idx] = src[map[row] * 150 + d];
}

__global__ void gcnk_concat(float* __restrict__ dst, const float* __restrict__ A,
                            const float* __restrict__ Bs, const int* __restrict__ mapA,
                            const int* __restrict__ mapB, const int* __restrict__ glen,
                            int usemask){
  int idx = blockIdx.x * 256 + threadIdx.x;
  if (idx >= 1600 * 300) return;
  int row = idx / 300, d = idx - row * 300;
  int b = row / 50, t = row - b * 50;
  float v;
  if (d < 150){ int r = mapA ? mapA[row] : row; v = A[r * 150 + d]; }
  else        { int r = mapB ? mapB[row] : row; v = Bs[r * 150 + d - 150]; }
  if (usemask && t >= glen[b]) v = 0.f;
  dst[idx] = v;
}

// ---------------- lstm whh -> fp16, rows padded 150 -> 152 ------------------
__global__ void gcnk_whhpack(const float* __restrict__ whh, _Float16* __restrict__ wpad){
  int idx = blockIdx.x * 256 + threadIdx.x;
  if (idx >= 1200 * 152) return;
  int row = idx / 152, col = idx - row * 152;
  wpad[idx] = (col < 150) ? (_Float16)whh[row * 150 + col] : (_Float16)0.f;
}

// ---------------- LSTM recurrence: weights in VGPRs, h fp16 in LDS ----------
__global__ __launch_bounds__(640)
void gcnk_lstm(const float* __restrict__ xf, const float* __restrict__ xr,
               const _Float16* __restrict__ wpad, float* __restrict__ fo,
               float* __restrict__ ro){
  int b = blockIdx.x >> 1, dir = blockIdx.x & 1;
  const float* xih = dir ? xr : xf;
  float* out = dir ? ro : fo;
  __shared__ __align__(16) _Float16 hh[160];
  __shared__ float gates[600];
  const int tid = threadIdx.x;

  h2 w[76];
  if (tid < 600){
    const h2* wrow = (const h2*)(wpad + ((size_t)dir * 600 + tid) * 152);
    #pragma unroll
    for (int j = 0; j < 76; j++) w[j] = wrow[j];
  }
  for (int u = tid; u < 160; u += 640) hh[u] = (_Float16)0.f;
  float creg = 0.f;
  __syncthreads();

  for (int t = 0; t < 50; t++){
    if (tid < 600){
      float acc = xih[(b * 50 + t) * 600 + tid];
      float a0 = 0.f, a1 = 0.f, a2 = 0.f, a3 = 0.f;   // break the dep chain 4-way
      #pragma unroll
      for (int j = 0; j < 19; j++){
        union { float4 f; h2 h[4]; } u;
        u.f = *(const float4*)(hh + j * 8);
        a0 = fdot2_(w[4 * j + 0], u.h[0], a0);
        a1 = fdot2_(w[4 * j + 1], u.h[1], a1);
        a2 = fdot2_(w[4 * j + 2], u.h[2], a2);
        a3 = fdot2_(w[4 * j + 3], u.h[3], a3);
      }
      gates[tid] = acc + ((a0 + a1) + (a2 + a3));
    }
    __syncthreads();
    if (tid < 150){
      float ig = sigm(gates[tid]);
      float fg = sigm(gates[150 + tid]);
      float gg = tanhf(gates[300 + tid]);
      float og = sigm(gates[450 + tid]);
      creg = fg * creg + ig * gg;
      float hn = og * tanhf(creg);
      hh[tid] = (_Float16)hn;
      out[(b * 50 + t) * 150 + tid] = hn;
    }
    __syncthreads();
  }
}

// ---------------- node feature assembly [17600 x 300] -----------------------
__global__ void gcnk_nodes_in(const int* __restrict__ x, const float* __restrict__ tab,
                              const float* __restrict__ cnnf, const float* __restrict__ lstmf,
                              float* __restrict__ out){
  int idx = blockIdx.x * 256 + threadIdx.x;
  if (idx >= NNODES * 300) return;
  int nrow = idx / 300, d = idx - nrow * 300;
  int b = nrow / 550, j = nrow - b * 550;
  float v;
  if (j < 500) v = tab[x[b * 500 + j] * 300 + d];
  else {
    int r = b * 50 + (j - 500);
    v = (d < 150) ? cnnf[r * 150 + d] : lstmf[r * 150 + d - 150];
  }
  out[idx] = v;
}

// ---------------- GCN: CSR build (counting sort by dst) ---------------------
__global__ void gcnk_hist(const int* __restrict__ ei, int* __restrict__ ecnt){
  int e = blockIdx.x * 256 + threadIdx.x;
  if (e < EDGES) atomicAdd(&ecnt[ei[EDGES + e]], 1);
}

// fast single-block scan: serial 18/thread + wave shfl scan + 16-entry scan
__global__ __launch_bounds__(1024)
void gcnk_scan(const int* __restrict__ ecnt, int* __restrict__ eoff,
               int* __restrict__ ecur){
  __shared__ int wsum[16];
  int tid = threadIdx.x;
  int base = tid * 18;
  int pre[18];
  int s = 0;
  #pragma unroll
  for (int i = 0; i < 18; i++){
    int idx = base + i;
    int c = (idx < NNODES) ? ecnt[idx] : 0;
    pre[i] = s; s += c;
  }
  int lane = tid & 63, wid = tid >> 6;
  int run = s;
  #pragma unroll
  for (int off = 1; off < 64; off <<= 1){
    int y = __shfl_up(run, off, 64);
    if (lane >= off) run += y;
  }
  if (lane == 63) wsum[wid] = run;
  __syncthreads();
  if (tid == 0){
    int a = 0;
    #pragma unroll
    for (int i = 0; i < 16; i++){ int t2 = wsum[i]; wsum[i] = a; a += t2; }
  }
  __syncthreads();
  int excl = wsum[wid] + run - s;
  #pragma unroll
  for (int i = 0; i < 18; i++){
    int idx = base + i;
    if (idx < NNODES){
      int e = excl + pre[i];
      eoff[idx] = e; ecur[idx] = e;
    }
  }
}

__global__ void gcnk_scatter(const int* __restrict__ ei, int* __restrict__ ecur,
                             int* __restrict__ esrc){
  int e = blockIdx.x * 256 + threadIdx.x;
  if (e < EDGES){
    int d = ei[EDGES + e];
    int p = atomicAdd(&ecur[d], 1);
    esrc[p] = ei[e];
  }
}

__global__ void gcnk_dis2(const int* __restrict__ ecnt, float* __restrict__ dis){
  int i = blockIdx.x * 256 + threadIdx.x;
  if (i < NNODES) dis[i] = rsqrtf((float)(ecnt[i] + 1));
}

// ---------------- GCN aggregation: fp16 gather + fused bias/elu epilogue ----
// xw is fp16 [NNODES][160] (cols >=150 unused). 128 thr/dst: t<75 owns h2.
__global__ __launch_bounds__(128)
void gcnk_aggcsr_h(const int* __restrict__ eoff, const int* __restrict__ ecnt,
                   const int* __restrict__ esrc, const float* __restrict__ dis,
                   const _Float16* __restrict__ xw, const float* __restrict__ bias,
                   float* __restrict__ out, int doelu){
  int d = blockIdx.x, t = threadIdx.x;
  float dd = dis[d];
  bool act = t < 75;
  float ax = 0.f, ay = 0.f;
  if (act){
    h2 v = *(const h2*)(xw + (size_t)d * 160 + 2 * t);
    ax = (float)v[0] * dd; ay = (float)v[1] * dd;
  }
  int beg = eoff[d], end = beg + ecnt[d];
  for (int j = beg; j < end; j++){
    int s = esrc[j];
    float ds_ = dis[s];
    if (act){
      h2 v = *(const h2*)(xw + (size_t)s * 160 + 2 * t);
      ax += (float)v[0] * ds_; ay += (float)v[1] * ds_;
    }
  }
  if (act){
    float o0 = ax * dd + bias[2 * t];
    float o1 = ay * dd + bias[2 * t + 1];
    if (doelu){
      o0 = (o0 > 0.f) ? o0 : expm1f(o0);
      o1 = (o1 > 0.f) ? o1 : expm1f(o1);
    }
    *(float2*)(out + (size_t)d * 150 + 2 * t) = make_float2(o0, o1);
  }
}

// ============================================================================
extern "C" void kernel_launch(void* const* d_in, const int* in_sizes, int n_in,
                              void* d_out, int out_size, void* d_ws, size_t ws_size,
                              hipStream_t stream){
  (void)in_sizes; (void)n_in; (void)out_size; (void)ws_size;

  char* wsb = (char*)d_ws;
  size_t off = 0;
  auto alloc = [&](size_t bytes) -> void* {
    void* p = wsb + off;
    off = (off + bytes + 255) & ~(size_t)255;
    return p;
  };
  float* pos_tab  = (float*)alloc(513 * 300 * 4);
  int*   sentlen  = (int*)alloc(1600 * 4);
  int*   glen     = (int*)alloc(32 * 4);
  int*   rowmap   = (int*)alloc(1600 * 4);
  float* ngram    = (float*)alloc(1600 * 300 * 4);
  float* cnn_feat = (float*)alloc(1600 * 150 * 4);
  float* cnn_rev  = (float*)alloc(1600 * 150 * 4);
  float* xih_f    = (float*)alloc(1600 * 600 * 4);
  float* xih_r    = (float*)alloc(1600 * 600 * 4);
  float* f0       = (float*)alloc(1600 * 150 * 4);
  float* r0       = (float*)alloc(1600 * 150 * 4);
  float* f1       = (float*)alloc(1600 * 150 * 4);
  float* r1       = (float*)alloc(1600 * 150 * 4);
  float* h1       = (float*)alloc(1600 * 300 * 4);
  float* h1rev    = (float*)alloc(1600 * 300 * 4);
  float* hm       = (float*)alloc(1600 * 300 * 4);
  float* lstm_ft  = (float*)alloc(1600 * 150 * 4);
  float* nodes_in = (float*)alloc((size_t)NNODES * 300 * 4);
  float* nodes    = (float*)alloc((size_t)NNODES * 150 * 4);
  float* dis      = (float*)alloc(NNODES * 4);
  _Float16* xwh   = (_Float16*)alloc((size_t)NNODES * 160 * 2);
  _Float16* ench  = (_Float16*)alloc((size_t)MPAD * 300 * 2);
  _Float16* Bp    = (_Float16*)alloc((size_t)2 * 160 * KSTRIDE * 2);
  float* bias_p   = (float*)alloc(320 * 4);
  _Float16* wpad0 = (_Float16*)alloc(1200 * 152 * 2);
  _Float16* wpad1 = (_Float16*)alloc(1200 * 152 * 2);
  int*   ecnt     = (int*)alloc(NNODES * 4);
  int*   eoff     = (int*)alloc(NNODES * 4);
  int*   ecur     = (int*)alloc(NNODES * 4);
  int*   esrc     = (int*)alloc(EDGES * 4);

  const int*   x   = (const int*)d_in[0];
  const int*   sx  = (const int*)d_in[1];
  const int*   ei  = (const int*)d_in[2];
  const float* tab = (const float*)d_in[3];
  const float *cw[6], *cb[6];
  for (int h = 0; h < 6; h++){ cw[h] = (const float*)d_in[4 + 2 * h]; cb[h] = (const float*)d_in[5 + 2 * h]; }
  const float* cnnw = (const float*)d_in[16]; const float* cnnb = (const float*)d_in[17];
  const float* wih0 = (const float*)d_in[18]; const float* whh0 = (const float*)d_in[19];
  const float* bih0 = (const float*)d_in[20]; const float* bhh0 = (const float*)d_in[21];
  const float* wih1 = (const float*)d_in[22]; const float* whh1 = (const float*)d_in[23];
  const float* bih1 = (const float*)d_in[24]; const float* bhh1 = (const float*)d_in[25];
  const float* lpw  = (const float*)d_in[26]; const float* lpb  = (const float*)d_in[27];
  const float* g0w  = (const float*)d_in[28]; const float* g0b  = (const float*)d_in[29];
  const float* g1w  = (const float*)d_in[30]; const float* g1b  = (const float*)d_in[31];
  const float* g2w  = (const float*)d_in[32]; const float* g2b  = (const float*)d_in[33];

  float* out0 = (float*)d_out;
  float4* out1 = (float4*)((float*)d_out + OUT0SZ);

  // big-M (17600 rows): 128x64 tile; small-M (1600 rows): 64x64 tile
  auto mgemmL = [&](const float* A, const float* W, const float* b1, const float* b2,
                    void* C, int M, int N, int K){
    dim3 g((M + 127) / 128, (N + 63) / 64);
    gcnk_mgemm<128, 64, 4, 2, 0><<<g, 256, 0, stream>>>(A, W, b1, b2, C, M, N, K);
  };
  auto mgemmLH = [&](const float* A, const float* W, void* C, int M, int N, int K){
    dim3 g((M + 127) / 128, (N + 63) / 64);
    gcnk_mgemm<128, 64, 4, 2, 1><<<g, 256, 0, stream>>>(A, W, nullptr, nullptr, C, M, N, K);
  };
  auto mgemmS = [&](const float* A, const float* W, const float* b1, const float* b2,
                    void* C, int M, int N, int K){
    dim3 g((M + 63) / 64, (N + 63) / 64);
    gcnk_mgemm<64, 64, 2, 2, 0><<<g, 256, 0, stream>>>(A, W, b1, b2, C, M, N, K);
  };

  // ---- pipeline ----
  gcnk_postab<<<602, 256, 0, stream>>>(pos_tab);
  gcnk_prep<<<7, 256, 0, stream>>>(sx, sentlen, glen);
  gcnk_rowmap<<<7, 256, 0, stream>>>(glen, rowmap);
  gcnk_embw<<<4688, 256, 0, stream>>>(x, tab, out1);

  // conv: fused implicit-im2col MFMA GEMM, K-split by head group
  gcnk_zeroi<<<1875, 256, 0, stream>>>((unsigned int*)ngram, 1600 * 300);
  gcnk_ench<<<(MPAD * 75 + 255) / 256, 256, 0, stream>>>(sx, tab, pos_tab, sentlen, ench);
  gcnk_bpack<<<(2 * 160 * KSTRIDE + 255) / 256, 256, 0, stream>>>(
      cw[0], cw[1], cw[2], cw[3], cw[4], cw[5],
      cb[0], cb[1], cb[2], cb[3], cb[4], cb[5], Bp, bias_p);
  gcnk_whhpack<<<713, 256, 0, stream>>>(whh0, wpad0);
  gcnk_whhpack<<<713, 256, 0, stream>>>(whh1, wpad1);
  {
    dim3 g(1000, 2);   // BM=64
    gcnk_convmfma<<<g, 256, 0, stream>>>(ench, Bp, bias_p, (unsigned int*)ngram);
  }
  gcnk_addpos<<<1875, 256, 0, stream>>>(ngram, pos_tab);
  mgemmS(ngram, cnnw, cnnb, nullptr, cnn_feat, 1600, 150, 300);

  // BiLSTM layer 0
  gcnk_permute150<<<938, 256, 0, stream>>>(cnn_rev, cnn_feat, rowmap);
  mgemmS(cnn_feat, wih0,             bih0,       bhh0,       xih_f, 1600, 600, 150);
  mgemmS(cnn_rev,  wih0 + 600 * 150, bih0 + 600, bhh0 + 600, xih_r, 1600, 600, 150);
  gcnk_lstm<<<64, 640, 0, stream>>>(xih_f, xih_r, wpad0, f0, r0);

  // BiLSTM layer 1
  gcnk_concat<<<1875, 256, 0, stream>>>(h1,    f0, r0, nullptr, rowmap, glen, 0);
  gcnk_concat<<<1875, 256, 0, stream>>>(h1rev, f0, r0, rowmap, nullptr, glen, 0);
  mgemmS(h1,    wih1,             bih1,       bhh1,       xih_f, 1600, 600, 300);
  mgemmS(h1rev, wih1 + 600 * 300, bih1 + 600, bhh1 + 600, xih_r, 1600, 600, 300);
  gcnk_lstm<<<64, 640, 0, stream>>>(xih_f, xih_r, wpad1, f1, r1);

  // masked projection
  gcnk_concat<<<1875, 256, 0, stream>>>(hm, f1, r1, nullptr, rowmap, glen, 1);
  mgemmS(hm, lpw, lpb, nullptr, lstm_ft, 1600, 150, 300);

  // node features + gc0
  gcnk_nodes_in<<<20625, 256, 0, stream>>>(x, tab, cnn_feat, lstm_ft, nodes_in);
  mgemmL(nodes_in, g0w, g0b, nullptr, nodes, NNODES, 150, 300);

  // CSR build (once, reused by both GCN layers)
  gcnk_zeroi<<<69, 256, 0, stream>>>((unsigned int*)ecnt, NNODES);
  gcnk_hist<<<2200, 256, 0, stream>>>(ei, ecnt);
  gcnk_scan<<<1, 1024, 0, stream>>>(ecnt, eoff, ecur);
  gcnk_scatter<<<2200, 256, 0, stream>>>(ei, ecur, esrc);
  gcnk_dis2<<<69, 256, 0, stream>>>(ecnt, dis);

  // gc1 + elu (fp16 xw gather, fused bias+elu epilogue)
  mgemmLH(nodes, g1w, xwh, NNODES, 150, 150);
  gcnk_aggcsr_h<<<NNODES, 128, 0, stream>>>(eoff, ecnt, esrc, dis, xwh, g1b, nodes, 1);

  // gc2 -> output 0 (fused bias epilogue)
  mgemmLH(nodes, g2w, xwh, NNODES, 150, 150);
  gcnk_aggcsr_h<<<NNODES, 128, 0, stream>>>(eoff, ecnt, esrc, dis, xwh, g2b, out0, 0);
}

// Round 2
// 828.979 us; speedup vs baseline: 1.1730x; 1.1730x over previous
//
#include <hip/hip_runtime.h>
#include <stdint.h>
#include <math.h>

// Problem constants (match reference)
#define EDGES 563200
#define NNODES 17600    // B*(NW+NS)
#define OUT0SZ 2640000  // 17600*150
#define MROWS 64000     // 1600 sentences * 40 positions
#define MPAD  64016     // + zero pad rows for window overhang
#define KSTRIDE 2112    // B pack row stride (halfs)

typedef _Float16 h2 __attribute__((ext_vector_type(2)));
typedef _Float16 h4 __attribute__((ext_vector_type(4)));
typedef _Float16 v8h __attribute__((ext_vector_type(8)));
typedef float v4f __attribute__((ext_vector_type(4)));

__device__ __forceinline__ float sigm(float x){ return 1.f / (1.f + expf(-x)); }

__device__ __forceinline__ float fdot2_(h2 a, h2 b, float c){
#if __has_builtin(__builtin_amdgcn_fdot2)
  return __builtin_amdgcn_fdot2(a, b, c, false);
#else
  return c + (float)a.x * (float)b.x + (float)a.y * (float)b.y;
#endif
}

// async global->LDS, 16B per lane; dest = wave-uniform base + lane*16
__device__ __forceinline__ void stage16(const char* g, char* lds_base, int lane){
#if __has_builtin(__builtin_amdgcn_global_load_lds)
  __builtin_amdgcn_global_load_lds(
      (const __attribute__((address_space(1))) void*)g,
      (__attribute__((address_space(3))) void*)lds_base, 16, 0, 0);
#else
  uint4 v = *(const uint4*)g;
  *(uint4*)(lds_base + lane * 16) = v;
#endif
}

// ---------------- POS table (numpy float64 sinusoid, row 0 zeroed) ----------
__global__ void gcnk_postab(float* __restrict__ pos){
  int idx = blockIdx.x * 256 + threadIdx.x;
  if (idx >= 513 * 300) return;
  int p = idx / 300, i = idx - p * 300;
  float v = 0.f;
  if (p != 0){
    double expo = (double)(2 * (i / 2)) / 300.0;
    double ang = (double)p / pow(10000.0, expo);
    v = (float)((i & 1) ? cos(ang) : sin(ang));
  }
  pos[idx] = v;
}

// ---------------- sentlen + glen --------------------------------------------
__global__ void gcnk_prep(const int* __restrict__ sx, int* __restrict__ sentlen,
                          int* __restrict__ glen){
  int tid = blockIdx.x * 256 + threadIdx.x;
  if (tid < 1600){
    int c = 0;
    for (int j = 0; j < 40; j++) c += (sx[tid * 40 + j] != 0);
    sentlen[tid] = c;
  } else if (tid < 1632){
    int b = tid - 1600, c = 0;
    for (int s = 0; s < 50; s++) c += (sx[b * 2000 + s * 40] != 0);
    glen[b] = c;
  }
}

__global__ void gcnk_rowmap(const int* __restrict__ glen, int* __restrict__ rowmap){
  int i = blockIdx.x * 256 + threadIdx.x;
  if (i >= 1600) return;
  int b = i / 50, t = i - b * 50, g = glen[b];
  rowmap[i] = b * 50 + ((t < g) ? (g - 1 - t) : t);
}

// ---------------- emb_words output ------------------------------------------
__global__ void gcnk_embw(const int* __restrict__ x, const float* __restrict__ tab,
                          float4* __restrict__ out){
  int idx = blockIdx.x * 256 + threadIdx.x;
  if (idx >= 16000 * 75) return;
  int row = idx / 75, q = idx - row * 75;
  const float4* t = (const float4*)tab;
  out[idx] = t[x[row] * 75 + q];
}

// ---------------- generic zero ----------------------------------------------
__global__ void gcnk_zeroi(unsigned int* __restrict__ p, int n){
  int i = blockIdx.x * 256 + threadIdx.x;
  if (i < n) p[i] = 0u;
}

// ---------------- enc (fp16): enc[m][d] = tab[tok]+pos, pad rows zero -------
__global__ void gcnk_ench(const int* __restrict__ sx, const float* __restrict__ tab,
                          const float* __restrict__ pos, const int* __restrict__ sentlen,
                          _Float16* __restrict__ ench){
  int idx = blockIdx.x * 256 + threadIdx.x;
  if (idx >= MPAD * 75) return;
  int row = idx / 75, q = idx - row * 75;
  int d = q * 4;
  h4 o; o[0] = (_Float16)0.f; o[1] = (_Float16)0.f; o[2] = (_Float16)0.f; o[3] = (_Float16)0.f;
  if (row < MROWS){
    int n = row / 40, l = row - n * 40;
    int tok = sx[n * 40 + l];
    int p = (l < sentlen[n]) ? (l + 1) : 0;
    float4 a = *(const float4*)(tab + (size_t)tok * 300 + d);
    float4 b = *(const float4*)(pos + (size_t)p * 300 + d);
    o[0] = (_Float16)(a.x + b.x); o[1] = (_Float16)(a.y + b.y);
    o[2] = (_Float16)(a.z + b.z); o[3] = (_Float16)(a.w + b.w);
  }
  *(h4*)(ench + (size_t)row * 300 + d) = o;
}

// ---------------- pack conv weights: Bp[2][160][2112] fp16 + bias[320] ------
// group g holds heads 3g+2..3g+4 (cols 0..149), cols 150..159 zero.
__global__ void gcnk_bpack(const float* w2, const float* w3, const float* w4,
                           const float* w5, const float* w6, const float* w7,
                           const float* c2, const float* c3, const float* c4,
                           const float* c5, const float* c6, const float* c7,
                           _Float16* __restrict__ Bp, float* __restrict__ bias_p){
  int idx = blockIdx.x * 256 + threadIdx.x;
  if (idx < 2 * 160 * KSTRIDE){
    int n = idx / KSTRIDE, kk = idx - n * KSTRIDE;
    int g = n / 160, c = n - g * 160;
    _Float16 v = (_Float16)0.f;
    if (c < 150){
      int H = 3 * g + 2 + c / 50, o = c % 50;
      if (kk < 300 * H){
        const float* w;
        switch (H){ case 2: w = w2; break; case 3: w = w3; break;
                    case 4: w = w4; break; case 5: w = w5; break;
                    case 6: w = w6; break; default: w = w7; break; }
        v = (_Float16)w[o * 300 * H + kk];
      }
    }
    Bp[idx] = v;
  }
  if (idx < 320){
    int g = idx / 160, c = idx - g * 160;
    float bv = 0.f;
    if (c < 150){
      int H = 3 * g + 2 + c / 50, o = c % 50;
      const float* cbp;
      switch (H){ case 2: cbp = c2; break; case 3: cbp = c3; break;
                  case 4: cbp = c4; break; case 5: cbp = c5; break;
                  case 6: cbp = c6; break; default: cbp = c7; break; }
      bv = cbp[o];
    }
    bias_p[idx] = bv;
  }
}

// ---------------- fused conv GEMM via MFMA f16 (m97-style) ------------------
// BM=128, BN=160, BK=64. Staging via global_load_lds(16B) with XOR-swizzled
// SOURCE address (T2 + rule #21): LDS[row][x] = logical[row][x ^ ((row&7)<<4)],
// ds_read_b128 applies the same XOR -> conflict-free fragment reads.
__global__ __launch_bounds__(256)
void gcnk_convmfma(const _Float16* __restrict__ A, const _Float16* __restrict__ Bp,
                   const float* __restrict__ bias_p, unsigned int* __restrict__ ngram_u){
  __shared__ __align__(1024) char smem[36864];
  _Float16* Asm = (_Float16*)smem;             // [128][64] halfs (128B/row)
  _Float16* Bsm = (_Float16*)(smem + 16384);   // [160][64] halfs
  float* Cs = (float*)smem;                    // epilogue reuse: [128][33]
  const int tid = threadIdx.x;
  const int m0 = blockIdx.x * 128;
  const int grp = blockIdx.y;
  const char* Abase = (const char*)A;
  const char* Bbase = (const char*)(Bp + (size_t)grp * 160 * KSTRIDE);
  const int kmax = grp ? 2112 : 1216;          // heads 2-4 need K<=1200
  const int w = tid >> 6, lane = tid & 63;
  const int wm = (w >> 1) * 64, wn = (w & 1) * 80;
  const int fm = lane & 15, fq = lane >> 4;
  const int lrow = lane >> 3;                              // 0..7
  const int loff = (((lane & 7) ^ lrow) << 4);             // swizzled src byte in 128B row

  v4f acc[4][5] = {};

  for (int kc = 0; kc < kmax; kc += 64){
    // stage A: 16 issues of 1KB (8 rows x 128B); wave w does issues 4w..4w+3
    #pragma unroll
    for (int ii = 0; ii < 4; ii++){
      int i = w * 4 + ii;
      const char* g = Abase + (size_t)(m0 + i * 8 + lrow) * 600 + kc * 2 + loff;
      stage16(g, (char*)Asm + i * 1024, lane);
    }
    // stage B: 20 issues; wave w does issues 5w..5w+4
    #pragma unroll
    for (int jj = 0; jj < 5; jj++){
      int j = w * 5 + jj;
      const char* g = Bbase + (size_t)(j * 8 + lrow) * (KSTRIDE * 2) + kc * 2 + loff;
      stage16(g, (char*)Bsm + j * 1024, lane);
    }
    __syncthreads();
    #pragma unroll
    for (int ks = 0; ks < 2; ks++){
      const int axor = (ks * 64 + fq * 16) ^ ((fm & 7) << 4);
      v8h af[4], bf[5];
      #pragma unroll
      for (int mt = 0; mt < 4; mt++)
        af[mt] = *(const v8h*)((const char*)Asm + (wm + mt * 16 + fm) * 128 + axor);
      #pragma unroll
      for (int nt = 0; nt < 5; nt++)
        bf[nt] = *(const v8h*)((const char*)Bsm + (wn + nt * 16 + fm) * 128 + axor);
      #pragma unroll
      for (int mt = 0; mt < 4; mt++)
        #pragma unroll
        for (int nt = 0; nt < 5; nt++)
          acc[mt][nt] = __builtin_amdgcn_mfma_f32_16x16x32_f16(af[mt], bf[nt], acc[mt][nt], 0, 0, 0);
    }
    __syncthreads();
  }

  // epilogue: 5 passes of 32 cols through LDS; relu+window-max -> atomicMax
  for (int p = 0; p < 5; p++){
    __syncthreads();
    #pragma unroll
    for (int nt = 0; nt < 5; nt++){
      int cstart = wn + nt * 16;
      if ((cstart >> 5) == p){
        int co = cstart - p * 32 + fm;
        #pragma unroll
        for (int mt = 0; mt < 4; mt++)
          #pragma unroll
          for (int r = 0; r < 4; r++)
            Cs[(wm + mt * 16 + fq * 4 + r) * 33 + co] = acc[mt][nt][r];
      }
    }
    __syncthreads();
    if (tid < 128){
      int cl = tid & 31, si = tid >> 5;        // 4 sentences can touch a 128-row tile
      int col = p * 32 + cl;                   // group-local col
      if (col < 150){
        int H = 3 * grp + 2 + col / 50, lh = 41 - H;
        int sent = m0 / 40 + si;
        if (sent < 1600){
          int rlo = sent * 40; if (rlo < m0) rlo = m0;
          int rhi = sent * 40 + lh; if (rhi > m0 + 128) rhi = m0 + 128;
          if (rlo < rhi){
            float bv = bias_p[grp * 160 + col];
            float vmax = 0.f;
            for (int r = rlo; r < rhi; r++){
              float v = Cs[(r - m0) * 33 + cl] + bv;
              vmax = fmaxf(vmax, v);
            }
            atomicMax(ngram_u + sent * 300 + grp * 150 + col, __float_as_uint(vmax));
          }
        }
      }
    }
  }
}

// ngram += POS_TAB[n % 50]
__global__ void gcnk_addpos(float* __restrict__ ngram, const float* __restrict__ pos){
  int idx = blockIdx.x * 256 + threadIdx.x;
  if (idx >= 1600 * 300) return;
  int row = idx / 300, d = idx - row * 300;
  ngram[idx] += pos[(row % 50) * 300 + d];
}

// ---------------- MFMA GEMM: C[M,N] = A[M,K](fp32->fp16) @ Wt[N,K]^T + b ----
// OUTH=1: write fp16 with row stride 160 (for the GCN aggregation gather).
template<int BM, int BN, int WMT, int WNT, int OUTH>
__global__ __launch_bounds__(256)
void gcnk_mgemm(const float* __restrict__ A, const float* __restrict__ Wt,
                const float* __restrict__ b1, const float* __restrict__ b2,
                void* __restrict__ Cv, int M, int N, int K){
  __shared__ __align__(16) _Float16 As[BM * 40];
  __shared__ __align__(16) _Float16 Bs[BN * 40];
  const int tid = threadIdx.x;
  const int m0 = blockIdx.x * BM, n0 = blockIdx.y * BN;
  const int w = tid >> 6, lane = tid & 63;
  const int wm = (w >> 1) * (WMT * 16), wn = (w & 1) * (WNT * 16);
  const int fm = lane & 15, fq = lane >> 4;
  v4f acc[WMT][WNT] = {};
  const int nch = (K + 31) >> 5;
  for (int ch = 0; ch < nch; ch++){
    int kc = ch * 32;
    #pragma unroll
    for (int j = 0; j < BM / 64; j++){      // A stage: BM rows x 32 halfs
      int u = tid + 256 * j;
      int row = u >> 2, cb = (u & 3) * 8;
      int gm = m0 + row, gk = kc + cb;
      v8h vv;
      if (gm < M && gk + 8 <= K){
        const float* p = A + (size_t)gm * K + gk;
        #pragma unroll
        for (int e = 0; e < 8; e++) vv[e] = (_Float16)p[e];
      } else {
        #pragma unroll
        for (int e = 0; e < 8; e++)
          vv[e] = (gm < M && gk + e < K) ? (_Float16)A[(size_t)gm * K + gk + e] : (_Float16)0.f;
      }
      *(v8h*)(As + row * 40 + cb) = vv;
    }
    {                                        // B stage: BN(=64) rows x 32 halfs
      int row = tid >> 2, cb = (tid & 3) * 8;
      int gn = n0 + row, gk = kc + cb;
      v8h vv;
      if (gn < N && gk + 8 <= K){
        const float* p = Wt + (size_t)gn * K + gk;
        #pragma unroll
        for (int e = 0; e < 8; e++) vv[e] = (_Float16)p[e];
      } else {
        #pragma unroll
        for (int e = 0; e < 8; e++)
          vv[e] = (gn < N && gk + e < K) ? (_Float16)Wt[(size_t)gn * K + gk + e] : (_Float16)0.f;
      }
      *(v8h*)(Bs + row * 40 + cb) = vv;
    }
    __syncthreads();
    v8h af[WMT], bf[WNT];
    #pragma unroll
    for (int mt = 0; mt < WMT; mt++)
      af[mt] = *(const v8h*)(As + (wm + mt * 16 + fm) * 40 + fq * 8);
    #pragma unroll
    for (int nt = 0; nt < WNT; nt++)
      bf[nt] = *(const v8h*)(Bs + (wn + nt * 16 + fm) * 40 + fq * 8);
    #pragma unroll
    for (int mt = 0; mt < WMT; mt++)
      #pragma unroll
      for (int nt = 0; nt < WNT; nt++)
        acc[mt][nt] = __builtin_amdgcn_mfma_f32_16x16x32_f16(af[mt], bf[nt], acc[mt][nt], 0, 0, 0);
    __syncthreads();
  }
  #pragma unroll
  for (int nt = 0; nt < WNT; nt++){
    int gn = n0 + wn + nt * 16 + fm;
    if (gn >= N) continue;
    float badd = (b1 ? b1[gn] : 0.f) + (b2 ? b2[gn] : 0.f);
    #pragma unroll
    for (int mt = 0; mt < WMT; mt++)
      #pragma unroll
      for (int r = 0; r < 4; r++){
        int gm = m0 + wm + mt * 16 + fq * 4 + r;
        if (gm < M){
          float val = acc[mt][nt][r] + badd;
          if (OUTH) ((_Float16*)Cv)[(size_t)gm * 160 + gn] = (_Float16)val;
          else      ((float*)Cv)[(size_t)gm * N + gn] = val;
        }
      }
  }
}

// ---------------- row permute / concat --------------------------------------
__global__ void gcnk_permute150(float* __restrict__ dst, const float* __restrict__ src,
                                const int* __restrict__ map){
  int idx = blockIdx.x * 256 + threadIdx.x;
  if (idx >= 1600 * 150) return;
  int row = idx / 150, d = idx - row * 150;
  dst[idx] = src[map[row] * 150 + d];
}

__global__ void gcnk_concat(float* __restrict__ dst, const float* __restrict__ A,
                            const float* __restrict__ Bs, const int* __restrict__ mapA,
                            const int* __restrict__ mapB, const int* __restrict__ glen,
                            int usemask){
  int idx = blockIdx.x * 256 + threadIdx.x;
  if (idx >= 1600 * 300) return;
  int row = idx / 300, d = idx - row * 300;
  int b = row / 50, t = row - b * 50;
  float v;
  if (d < 150){ int r = mapA ? mapA[row] : row; v = A[r * 150 + d]; }
  else        { int r = mapB ? mapB[row] : row; v = Bs[r * 150 + d - 150]; }
  if (usemask && t >= glen[b]) v = 0.f;
  dst[idx] = v;
}

// ---------------- lstm whh -> fp16, rows padded 150 -> 152 ------------------
__global__ void gcnk_whhpack(const float* __restrict__ whh, _Float16* __restrict__ wpad){
  int idx = blockIdx.x * 256 + threadIdx.x;
  if (idx >= 1200 * 152) return;
  int row = idx / 152, col = idx - row * 152;
  wpad[idx] = (col < 150) ? (_Float16)whh[row * 150 + col] : (_Float16)0.f;
}

// ---------------- LSTM recurrence: weights in VGPRs, h fp16 in LDS ----------
__global__ __launch_bounds__(640)
void gcnk_lstm(const float* __restrict__ xf, const float* __restrict__ xr,
               const _Float16* __restrict__ wpad, float* __restrict__ fo,
               float* __restrict__ ro){
  int b = blockIdx.x >> 1, dir = blockIdx.x & 1;
  const float* xih = dir ? xr : xf;
  float* out = dir ? ro : fo;
  __shared__ __align__(16) _Float16 hh[160];
  __shared__ float gates[600];
  const int tid = threadIdx.x;

  h2 w[76];
  if (tid < 600){
    const h2* wrow = (const h2*)(wpad + ((size_t)dir * 600 + tid) * 152);
    #pragma unroll
    for (int j = 0; j < 76; j++) w[j] = wrow[j];
  }
  for (int u = tid; u < 160; u += 640) hh[u] = (_Float16)0.f;
  float creg = 0.f;
  __syncthreads();

  for (int t = 0; t < 50; t++){
    if (tid < 600){
      float acc = xih[(b * 50 + t) * 600 + tid];
      float a0 = 0.f, a1 = 0.f, a2 = 0.f, a3 = 0.f;   // break the dep chain 4-way
      #pragma unroll
      for (int j = 0; j < 19; j++){
        union { float4 f; h2 h[4]; } u;
        u.f = *(const float4*)(hh + j * 8);
        a0 = fdot2_(w[4 * j + 0], u.h[0], a0);
        a1 = fdot2_(w[4 * j + 1], u.h[1], a1);
        a2 = fdot2_(w[4 * j + 2], u.h[2], a2);
        a3 = fdot2_(w[4 * j + 3], u.h[3], a3);
      }
      gates[tid] = acc + ((a0 + a1) + (a2 + a3));
    }
    __syncthreads();
    if (tid < 150){
      float ig = sigm(gates[tid]);
      float fg = sigm(gates[150 + tid]);
      float gg = tanhf(gates[300 + tid]);
      float og = sigm(gates[450 + tid]);
      creg = fg * creg + ig * gg;
      float hn = og * tanhf(creg);
      hh[tid] = (_Float16)hn;
      out[(b * 50 + t) * 150 + tid] = hn;
    }
    __syncthreads();
  }
}

// ---------------- node feature assembly [17600 x 300] -----------------------
__global__ void gcnk_nodes_in(const int* __restrict__ x, const float* __restrict__ tab,
                              const float* __restrict__ cnnf, const float* __restrict__ lstmf,
                              float* __restrict__ out){
  int idx = blockIdx.x * 256 + threadIdx.x;
  if (idx >= NNODES * 300) return;
  int nrow = idx / 300, d = idx - nrow * 300;
  int b = nrow / 550, j = nrow - b * 550;
  float v;
  if (j < 500) v = tab[x[b * 500 + j] * 300 + d];
  else {
    int r = b * 50 + (j - 500);
    v = (d < 150) ? cnnf[r * 150 + d] : lstmf[r * 150 + d - 150];
  }
  out[idx] = v;
}

// ---------------- GCN: CSR build (counting sort by dst) ---------------------
__global__ void gcnk_hist(const int* __restrict__ ei, int* __restrict__ ecnt){
  int e = blockIdx.x * 256 + threadIdx.x;
  if (e < EDGES) atomicAdd(&ecnt[ei[EDGES + e]], 1);
}

// fast single-block scan: serial 18/thread + wave shfl scan + 16-entry scan
__global__ __launch_bounds__(1024)
void gcnk_scan(const int* __restrict__ ecnt, int* __restrict__ eoff,
               int* __restrict__ ecur){
  __shared__ int wsum[16];
  int tid = threadIdx.x;
  int base = tid * 18;
  int pre[18];
  int s = 0;
  #pragma unroll
  for (int i = 0; i < 18; i++){
    int idx = base + i;
    int c = (idx < NNODES) ? ecnt[idx] : 0;
    pre[i] = s; s += c;
  }
  int lane = tid & 63, wid = tid >> 6;
  int run = s;
  #pragma unroll
  for (int off = 1; off < 64; off <<= 1){
    int y = __shfl_up(run, off, 64);
    if (lane >= off) run += y;
  }
  if (lane == 63) wsum[wid] = run;
  __syncthreads();
  if (tid == 0){
    int a = 0;
    #pragma unroll
    for (int i = 0; i < 16; i++){ int t2 = wsum[i]; wsum[i] = a; a += t2; }
  }
  __syncthreads();
  int excl = wsum[wid] + run - s;
  #pragma unroll
  for (int i = 0; i < 18; i++){
    int idx = base + i;
    if (idx < NNODES){
      int e = excl + pre[i];
      eoff[idx] = e; ecur[idx] = e;
    }
  }
}

__global__ void gcnk_scatter(const int* __restrict__ ei, int* __restrict__ ecur,
                             int* __restrict__ esrc){
  int e = blockIdx.x * 256 + threadIdx.x;
  if (e < EDGES){
    int d = ei[EDGES + e];
    int p = atomicAdd(&ecur[d], 1);
    esrc[p] = ei[e];
  }
}

__global__ void gcnk_dis2(const int* __restrict__ ecnt, float* __restrict__ dis){
  int i = blockIdx.x * 256 + threadIdx.x;
  if (i < NNODES) dis[i] = rsqrtf((float)(ecnt[i] + 1));
}

// ---------------- GCN aggregation: fp16 gather + fused bias/elu epilogue ----
// xw is fp16 [NNODES][160] (cols >=150 unused). 128 thr/dst: t<75 owns h2.
__global__ __launch_bounds__(128)
void gcnk_aggcsr_h(const int* __restrict__ eoff, const int* __restrict__ ecnt,
                   const int* __restrict__ esrc, const float* __restrict__ dis,
                   const _Float16* __restrict__ xw, const float* __restrict__ bias,
                   float* __restrict__ out, int doelu){
  int d = blockIdx.x, t = threadIdx.x;
  float dd = dis[d];
  bool act = t < 75;
  float ax = 0.f, ay = 0.f;
  if (act){
    h2 v = *(const h2*)(xw + (size_t)d * 160 + 2 * t);
    ax = (float)v[0] * dd; ay = (float)v[1] * dd;
  }
  int beg = eoff[d], end = beg + ecnt[d];
  for (int j = beg; j < end; j++){
    int s = esrc[j];
    float ds_ = dis[s];
    if (act){
      h2 v = *(const h2*)(xw + (size_t)s * 160 + 2 * t);
      ax += (float)v[0] * ds_; ay += (float)v[1] * ds_;
    }
  }
  if (act){
    float o0 = ax * dd + bias[2 * t];
    float o1 = ay * dd + bias[2 * t + 1];
    if (doelu){
      o0 = (o0 > 0.f) ? o0 : expm1f(o0);
      o1 = (o1 > 0.f) ? o1 : expm1f(o1);
    }
    *(float2*)(out + (size_t)d * 150 + 2 * t) = make_float2(o0, o1);
  }
}

// ============================================================================
extern "C" void kernel_launch(void* const* d_in, const int* in_sizes, int n_in,
                              void* d_out, int out_size, void* d_ws, size_t ws_size,
                              hipStream_t stream){
  (void)in_sizes; (void)n_in; (void)out_size; (void)ws_size;

  char* wsb = (char*)d_ws;
  size_t off = 0;
  auto alloc = [&](size_t bytes) -> void* {
    void* p = wsb + off;
    off = (off + bytes + 255) & ~(size_t)255;
    return p;
  };
  float* pos_tab  = (float*)alloc(513 * 300 * 4);
  int*   sentlen  = (int*)alloc(1600 * 4);
  int*   glen     = (int*)alloc(32 * 4);
  int*   rowmap   = (int*)alloc(1600 * 4);
  float* ngram    = (float*)alloc(1600 * 300 * 4);
  float* cnn_feat = (float*)alloc(1600 * 150 * 4);
  float* cnn_rev  = (float*)alloc(1600 * 150 * 4);
  float* xih_f    = (float*)alloc(1600 * 600 * 4);
  float* xih_r    = (float*)alloc(1600 * 600 * 4);
  float* f0       = (float*)alloc(1600 * 150 * 4);
  float* r0       = (float*)alloc(1600 * 150 * 4);
  float* f1       = (float*)alloc(1600 * 150 * 4);
  float* r1       = (float*)alloc(1600 * 150 * 4);
  float* h1       = (float*)alloc(1600 * 300 * 4);
  float* h1rev    = (float*)alloc(1600 * 300 * 4);
  float* hm       = (float*)alloc(1600 * 300 * 4);
  float* lstm_ft  = (float*)alloc(1600 * 150 * 4);
  float* nodes_in = (float*)alloc((size_t)NNODES * 300 * 4);
  float* nodes    = (float*)alloc((size_t)NNODES * 150 * 4);
  float* dis      = (float*)alloc(NNODES * 4);
  _Float16* xwh   = (_Float16*)alloc((size_t)NNODES * 160 * 2);
  _Float16* ench  = (_Float16*)alloc((size_t)MPAD * 300 * 2);
  _Float16* Bp    = (_Float16*)alloc((size_t)2 * 160 * KSTRIDE * 2);
  float* bias_p   = (float*)alloc(320 * 4);
  _Float16* wpad0 = (_Float16*)alloc(1200 * 152 * 2);
  _Float16* wpad1 = (_Float16*)alloc(1200 * 152 * 2);
  int*   ecnt     = (int*)alloc(NNODES * 4);
  int*   eoff     = (int*)alloc(NNODES * 4);
  int*   ecur     = (int*)alloc(NNODES * 4);
  int*   esrc     = (int*)alloc(EDGES * 4);

  const int*   x   = (const int*)d_in[0];
  const int*   sx  = (const int*)d_in[1];
  const int*   ei  = (const int*)d_in[2];
  const float* tab = (const float*)d_in[3];
  const float *cw[6], *cb[6];
  for (int h = 0; h < 6; h++){ cw[h] = (const float*)d_in[4 + 2 * h]; cb[h] = (const float*)d_in[5 + 2 * h]; }
  const float* cnnw = (const float*)d_in[16]; const float* cnnb = (const float*)d_in[17];
  const float* wih0 = (const float*)d_in[18]; const float* whh0 = (const float*)d_in[19];
  const float* bih0 = (const float*)d_in[20]; const float* bhh0 = (const float*)d_in[21];
  const float* wih1 = (const float*)d_in[22]; const float* whh1 = (const float*)d_in[23];
  const float* bih1 = (const float*)d_in[24]; const float* bhh1 = (const float*)d_in[25];
  const float* lpw  = (const float*)d_in[26]; const float* lpb  = (const float*)d_in[27];
  const float* g0w  = (const float*)d_in[28]; const float* g0b  = (const float*)d_in[29];
  const float* g1w  = (const float*)d_in[30]; const float* g1b  = (const float*)d_in[31];
  const float* g2w  = (const float*)d_in[32]; const float* g2b  = (const float*)d_in[33];

  float* out0 = (float*)d_out;
  float4* out1 = (float4*)((float*)d_out + OUT0SZ);

  // big-M (17600 rows): 128x64 tile; small-M (1600 rows): 64x64 tile
  auto mgemmL = [&](const float* A, const float* W, const float* b1, const float* b2,
                    void* C, int M, int N, int K){
    dim3 g((M + 127) / 128, (N + 63) / 64);
    gcnk_mgemm<128, 64, 4, 2, 0><<<g, 256, 0, stream>>>(A, W, b1, b2, C, M, N, K);
  };
  auto mgemmLH = [&](const float* A, const float* W, void* C, int M, int N, int K){
    dim3 g((M + 127) / 128, (N + 63) / 64);
    gcnk_mgemm<128, 64, 4, 2, 1><<<g, 256, 0, stream>>>(A, W, nullptr, nullptr, C, M, N, K);
  };
  auto mgemmS = [&](const float* A, const float* W, const float* b1, const float* b2,
                    void* C, int M, int N, int K){
    dim3 g((M + 63) / 64, (N + 63) / 64);
    gcnk_mgemm<64, 64, 2, 2, 0><<<g, 256, 0, stream>>>(A, W, b1, b2, C, M, N, K);
  };

  // ---- pipeline ----
  gcnk_postab<<<602, 256, 0, stream>>>(pos_tab);
  gcnk_prep<<<7, 256, 0, stream>>>(sx, sentlen, glen);
  gcnk_rowmap<<<7, 256, 0, stream>>>(glen, rowmap);
  gcnk_embw<<<4688, 256, 0, stream>>>(x, tab, out1);

  // conv: fused implicit-im2col MFMA GEMM, K-split by head group
  gcnk_zeroi<<<1875, 256, 0, stream>>>((unsigned int*)ngram, 1600 * 300);
  gcnk_ench<<<(MPAD * 75 + 255) / 256, 256, 0, stream>>>(sx, tab, pos_tab, sentlen, ench);
  gcnk_bpack<<<(2 * 160 * KSTRIDE + 255) / 256, 256, 0, stream>>>(
      cw[0], cw[1], cw[2], cw[3], cw[4], cw[5],
      cb[0], cb[1], cb[2], cb[3], cb[4], cb[5], Bp, bias_p);
  gcnk_whhpack<<<713, 256, 0, stream>>>(whh0, wpad0);
  gcnk_whhpack<<<713, 256, 0, stream>>>(whh1, wpad1);
  {
    dim3 g(500, 2);   // BM=128
    gcnk_convmfma<<<g, 256, 0, stream>>>(ench, Bp, bias_p, (unsigned int*)ngram);
  }
  gcnk_addpos<<<1875, 256, 0, stream>>>(ngram, pos_tab);
  mgemmS(ngram, cnnw, cnnb, nullptr, cnn_feat, 1600, 150, 300);

  // BiLSTM layer 0
  gcnk_permute150<<<938, 256, 0, stream>>>(cnn_rev, cnn_feat, rowmap);
  mgemmS(cnn_feat, wih0,             bih0,       bhh0,       xih_f, 1600, 600, 150);
  mgemmS(cnn_rev,  wih0 + 600 * 150, bih0 + 600, bhh0 + 600, xih_r, 1600, 600, 150);
  gcnk_lstm<<<64, 640, 0, stream>>>(xih_f, xih_r, wpad0, f0, r0);

  // BiLSTM layer 1
  gcnk_concat<<<1875, 256, 0, stream>>>(h1,    f0, r0, nullptr, rowmap, glen, 0);
  gcnk_concat<<<1875, 256, 0, stream>>>(h1rev, f0, r0, rowmap, nullptr, glen, 0);
  mgemmS(h1,    wih1,             bih1,       bhh1,       xih_f, 1600, 600, 300);
  mgemmS(h1rev, wih1 + 600 * 300, bih1 + 600, bhh1 + 600, xih_r, 1600, 600, 300);
  gcnk_lstm<<<64, 640, 0, stream>>>(xih_f, xih_r, wpad1, f1, r1);

  // masked projection
  gcnk_concat<<<1875, 256, 0, stream>>>(hm, f1, r1, nullptr, rowmap, glen, 1);
  mgemmS(hm, lpw, lpb, nullptr, lstm_ft, 1600, 150, 300);

  // node features + gc0
  gcnk_nodes_in<<<20625, 256, 0, stream>>>(x, tab, cnn_feat, lstm_ft, nodes_in);
  mgemmL(nodes_in, g0w, g0b, nullptr, nodes, NNODES, 150, 300);

  // CSR build (once, reused by both GCN layers)
  gcnk_zeroi<<<69, 256, 0, stream>>>((unsigned int*)ecnt, NNODES);
  gcnk_hist<<<2200, 256, 0, stream>>>(ei, ecnt);
  gcnk_scan<<<1, 1024, 0, stream>>>(ecnt, eoff, ecur);
  gcnk_scatter<<<2200, 256, 0, stream>>>(ei, ecur, esrc);
  gcnk_dis2<<<69, 256, 0, stream>>>(ecnt, dis);

  // gc1 + elu (fp16 xw gather, fused bias+elu epilogue)
  mgemmLH(nodes, g1w, xwh, NNODES, 150, 150);
  gcnk_aggcsr_h<<<NNODES, 128, 0, stream>>>(eoff, ecnt, esrc, dis, xwh, g1b, nodes, 1);

  // gc2 -> output 0 (fused bias epilogue)
  mgemmLH(nodes, g2w, xwh, NNODES, 150, 150);
  gcnk_aggcsr_h<<<NNODES, 128, 0, stream>>>(eoff, ecnt, esrc, dis, xwh, g2b, out0, 0);
}